// Round 6
// baseline (33.469 us; speedup 1.0000x reference)
//
#include <hip/hip_runtime.h>
#include <hip/hip_bf16.h>

#define MM 64
#define KTOT 4096
#define NN 11008
#define PACKS 1376    // NN / 8
#define BN 128
#define NBLK 86       // NN / BN
#define KSPLIT 8
#define BKCHUNK 512   // KTOT / KSPLIT
#define BK 64         // k per step
#define NSTEP 8       // BKCHUNK / BK
#define NBLOCKS (NBLK * KSPLIT)  // 688

typedef float f32x4 __attribute__((ext_vector_type(4)));
typedef short bf16x8 __attribute__((ext_vector_type(8)));

__device__ __forceinline__ unsigned int f2bf(float f) {
    unsigned int b = __float_as_uint(f);
    return (b + 0x7FFFu + ((b >> 16) & 1u)) >> 16;   // RNE to bf16
}

// prep: convert x f32 -> bf16 into d_ws (512 KB)
__global__ __launch_bounds__(256) void prep(const float* __restrict__ x,
                                            unsigned short* __restrict__ xbf) {
    const int t = blockIdx.x * 256 + threadIdx.x;   // 32768 threads
    const float4 v0 = reinterpret_cast<const float4*>(x)[t * 2];
    const float4 v1 = reinterpret_cast<const float4*>(x)[t * 2 + 1];
    uint4 o;
    o.x = f2bf(v0.x) | (f2bf(v0.y) << 16);
    o.y = f2bf(v0.z) | (f2bf(v0.w) << 16);
    o.z = f2bf(v1.x) | (f2bf(v1.y) << 16);
    o.w = f2bf(v1.z) | (f2bf(v1.w) << 16);
    reinterpret_cast<uint4*>(xbf)[t] = o;
}

// 512-thread coalesced-staging AWQ GEMM. 8 waves, each owns 16 n-cols x 64 m.
__global__ __launch_bounds__(512, 4) void awq_mfma(
    const unsigned short* __restrict__ xbf, const int* __restrict__ qw,
    const int* __restrict__ qz, const float* __restrict__ sc,
    float* __restrict__ part)
{
    // raw qweight staging: [dbuf][64 k-rows][16 dwords + 2 pad]
    __shared__ __attribute__((aligned(16))) unsigned int qst[2][64][18];
    // x tile: [dbuf][64 m-rows][32 dwords], 16B slots XOR-swizzled by row&7
    __shared__ __attribute__((aligned(16))) unsigned int xst[2][64][32];
    // dequanted W tiles, wave-private single-buffer: [wave][16 n][32 dwords]
    __shared__ __attribute__((aligned(16))) unsigned int wtl[8][16][32];

    const int tid = threadIdx.x, wv = tid >> 6, l = tid & 63;
    const int bid = blockIdx.x;
    const int ks  = bid & 7;            // k-stripe == XCD (round-robin dispatch)
    const int bn  = bid >> 3;           // adjacent bn share an XCD's L2
    const int k00 = ks * BKCHUNK;
    const int l15 = l & 15, l4 = l >> 4;

    // block-cooperative staging mappings
    const int qrow = tid >> 3, qdw = (tid & 7) * 2;   // 64 rows x 16 dw (64B dense)
    const int xrow = tid >> 3, xsl = tid & 7;         // 64 rows x 8 slots of 16B
    // wave-local dequant mapping: k-pair t2 (0..31), pack-col pc (0..1)
    const int t2 = l >> 1, pc = l & 1;
    const int cg = bn * 16 + wv * 2 + pc;             // global pack-col

    const int* qsrc = qw + (k00 + qrow) * PACKS + bn * 16 + qdw;
    const unsigned short* xsrc = xbf + xrow * KTOT + k00 + xsl * 8;

    unsigned int (*my)[32] = wtl[wv];

    // W-tile write dword indices (loop-invariant): n = pc*8+j, col = t2 swizzled
    int widx[8];
#pragma unroll
    for (int j = 0; j < 8; ++j) {
        const int n = pc * 8 + j;
        widx[j] = n * 32 + (t2 ^ ((n & 7) << 2));
    }

    uint2 qreg[2];
    uint4 xreg[2];
    int zzc, zzn;
    float4 s0c, s1c, s0n, s1n;
    float sj[8], nzs[8];
    f32x4 acc[4] = {};

    // prologue: step-0 staging regs + group-0 scales
    qreg[0] = *reinterpret_cast<const uint2*>(qsrc);
    xreg[0] = *reinterpret_cast<const uint4*>(xsrc);
    {
        const int g = k00 >> 7;
        zzc = qz[g * PACKS + cg];
        s0c = *reinterpret_cast<const float4*>(sc + g * NN + cg * 8);
        s1c = *reinterpret_cast<const float4*>(sc + g * NN + cg * 8 + 4);
    }

#pragma unroll
    for (int st = 0; st < NSTEP; ++st) {
        const int B = st & 1, P = B ^ 1;

        // prefetch next step's staging into regs (stays in flight across barrier)
        if (st + 1 < NSTEP) {
            qreg[P] = *reinterpret_cast<const uint2*>(qsrc + (st + 1) * BK * PACKS);
            xreg[P] = *reinterpret_cast<const uint4*>(xsrc + (st + 1) * BK);
        }
        // group boundary every 2 steps (GROUP_SIZE=128, BK=64)
        if ((st & 1) == 0) {
            if (st) { zzc = zzn; s0c = s0n; s1c = s1n; }
            const float sjl[8] = { s0c.x, s0c.y, s0c.z, s0c.w,
                                   s1c.x, s1c.y, s1c.z, s1c.w };
#pragma unroll
            for (int j = 0; j < 8; ++j) {
                const int sh = ((j >> 1) << 2) + ((j & 1) << 4);
                sj[j]  = sjl[j];
                nzs[j] = -(float)((zzc >> sh) & 0xF) * sjl[j];
            }
            if (st + 2 < NSTEP) {
                const int g = (k00 + (st + 2) * BK) >> 7;
                zzn = qz[g * PACKS + cg];
                s0n = *reinterpret_cast<const float4*>(sc + g * NN + cg * 8);
                s1n = *reinterpret_cast<const float4*>(sc + g * NN + cg * 8 + 4);
            }
        }

        // staging writes (regs loaded one step ago; compiler inserts counted vmcnt)
        *reinterpret_cast<uint2*>(&qst[B][qrow][qdw]) = qreg[B];
        *reinterpret_cast<uint4*>(&xst[B][xrow][(xsl ^ (xrow & 7)) << 2]) = xreg[B];

        // one barrier per step: drain LDS writes only, globals stay in flight
        asm volatile("s_waitcnt lgkmcnt(0)\n\ts_barrier" ::: "memory");

        // ---- dequant from staging (AWQ nibble order: sh = (j>>1)*4 + (j&1)*16) ----
        const int q0 = qst[B][2 * t2    ][wv * 2 + pc];
        const int q1 = qst[B][2 * t2 + 1][wv * 2 + pc];
        unsigned int* wbuf = &wtl[wv][0][0];
#pragma unroll
        for (int j = 0; j < 8; ++j) {
            const int sh = ((j >> 1) << 2) + ((j & 1) << 4);
            const float w0 = fmaf((float)((q0 >> sh) & 0xF), sj[j], nzs[j]);
            const float w1 = fmaf((float)((q1 >> sh) & 0xF), sj[j], nzs[j]);
            unsigned int pr;
            asm("v_cvt_pk_bf16_f32 %0, %1, %2" : "=v"(pr) : "v"(w0), "v"(w1));
            wbuf[widx[j]] = pr;     // (k even, k odd) pair
        }

        // ---- fragments + MFMA (wave-private W-tile: in-order DS, no barrier) ----
#pragma unroll
        for (int kk = 0; kk < 2; ++kk) {
            bf16x8 bfr;
            {
                const int c = (kk * 16 + l4 * 4) ^ ((l15 & 7) << 2);
                bfr = *reinterpret_cast<const bf16x8*>(&my[l15][c]);
            }
#pragma unroll
            for (int mt = 0; mt < 4; ++mt) {
                const int r = mt * 16 + l15;
                const int c = (kk * 16 + l4 * 4) ^ ((r & 7) << 2);
                const bf16x8 af = *reinterpret_cast<const bf16x8*>(&xst[B][r][c]);
                acc[mt] = __builtin_amdgcn_mfma_f32_16x16x32_bf16(af, bfr, acc[mt], 0, 0, 0);
            }
        }
    }

    // ---- epilogue: plain stores (C/D: col=lane&15, row=(lane>>4)*4+r) ----
    float* pout = part + ks * (MM * NN) + bn * BN + wv * 16;
#pragma unroll
    for (int mt = 0; mt < 4; ++mt) {
        const int r0 = mt * 16 + l4 * 4;
#pragma unroll
        for (int r = 0; r < 4; ++r)
            pout[(r0 + r) * NN + l15] = acc[mt][r];
    }
}

// reduce: out = bias + sum_ks part[ks]
__global__ __launch_bounds__(256) void reduce_k(const float* __restrict__ part,
                                                const float* __restrict__ bias,
                                                float* __restrict__ out) {
    const int t = blockIdx.x * 256 + threadIdx.x;   // float4 idx, 176128 total
    const int n = (t * 4) % NN;
    float4 s = reinterpret_cast<const float4*>(part)[t];
#pragma unroll
    for (int ks = 1; ks < KSPLIT; ++ks) {
        const float4 v = reinterpret_cast<const float4*>(part + ks * (MM * NN))[t];
        s.x += v.x; s.y += v.y; s.z += v.z; s.w += v.w;
    }
    const float4 b = *reinterpret_cast<const float4*>(bias + n);
    s.x += b.x; s.y += b.y; s.z += b.z; s.w += b.w;
    reinterpret_cast<float4*>(out)[t] = s;
}

extern "C" void kernel_launch(void* const* d_in, const int* in_sizes, int n_in,
                              void* d_out, int out_size, void* d_ws, size_t ws_size,
                              hipStream_t stream) {
    const float* x    = (const float*)d_in[0];
    const int*   qw   = (const int*)d_in[1];
    const int*   qz   = (const int*)d_in[2];
    const float* sc   = (const float*)d_in[3];
    const float* bias = (const float*)d_in[4];
    float* out = (float*)d_out;

    unsigned short* xbf = (unsigned short*)d_ws;                                  // 512 KB
    float* part = (float*)((char*)d_ws + MM * KTOT * sizeof(unsigned short));     // 22.5 MB

    prep<<<dim3(MM * KTOT / 8 / 256), 256, 0, stream>>>(x, xbf);
    awq_mfma<<<dim3(NBLOCKS), 512, 0, stream>>>(xbf, qw, qz, sc, part);
    reduce_k<<<dim3(MM * NN / 4 / 256), 256, 0, stream>>>(part, bias, out);
}